// Round 3
// baseline (681.548 us; speedup 1.0000x reference)
//
#include <hip/hip_runtime.h>
#include <hip/hip_bf16.h>
#include <stdint.h>

// Problem constants (fixed by the reference)
#define B_ 8
#define T_ 128
#define U_ 64
#define D_ 1024
#define V_ 1024
// M_total = B*T*U = 65536

typedef __attribute__((ext_vector_type(8))) short short8v;   // 8 bf16 (4 VGPRs)
typedef __attribute__((ext_vector_type(4))) float floatx4;   // MFMA accumulator

typedef __attribute__((address_space(3))) uint8_t lds_u8_t;
typedef __attribute__((address_space(1))) uint8_t glb_u8_t;

// fp32 -> bf16, round-to-nearest-even (scalar, used in prep_w)
__device__ __forceinline__ unsigned short f2bf(float f) {
  union { float f; uint32_t u; } c; c.f = f;
  const uint32_t u = c.u;
  return (unsigned short)((u + 0x7fffu + ((u >> 16) & 1u)) >> 16);
}

// packed pair conversion: two fp32 -> one dword of 2 bf16 (RNE).
__device__ __forceinline__ unsigned cvt2(float a, float b) {
  float2 t; t.x = a; t.y = b;
  __hip_bfloat162 h = __float22bfloat162_rn(t);
  union { __hip_bfloat162 h; unsigned u; } c; c.h = h;
  return c.u;
}

// ---------------------------------------------------------------------------
// prep_w: W[k][v] fp32  ->  Wt[v][k] bf16, pre-swizzled within each 64-k group
// (T2/m201 pattern: linear gload_lds dest + inverse-swizzled source + swizzled
// ds_read). Grid: (D/64, V/64) blocks x 256 threads.
// ---------------------------------------------------------------------------
__global__ void prep_w(const float* __restrict__ W, unsigned short* __restrict__ Wt) {
  __shared__ float tile[64][65];           // [k][v], +1 pad
  const int k0 = blockIdx.x * 64;
  const int v0 = blockIdx.y * 64;
  const int tid = threadIdx.x;
#pragma unroll
  for (int c = 0; c < 4; ++c) {            // 1024 float4 slots, coalesced over v
    const int lin = tid + c * 256;
    const int kk = lin >> 4;
    const int vv = (lin & 15) << 2;
    const float4 f = *reinterpret_cast<const float4*>(&W[(size_t)(k0 + kk) * V_ + v0 + vv]);
    tile[kk][vv + 0] = f.x; tile[kk][vv + 1] = f.y;
    tile[kk][vv + 2] = f.z; tile[kk][vv + 3] = f.w;
  }
  __syncthreads();
#pragma unroll
  for (int c = 0; c < 2; ++c) {            // 512 chunk-writes of 8 bf16 (16B)
    const int w = tid + c * 256;
    const int vv = w >> 3;                 // v within tile
    const int p  = w & 7;                  // stored chunk position in row
    const int lc = p ^ (vv & 7);           // logical k-chunk held at position p
    short8v val;
#pragma unroll
    for (int j = 0; j < 8; ++j) val[j] = (short)f2bf(tile[lc * 8 + j][vv]);
    *reinterpret_cast<short8v*>(&Wt[(size_t)(v0 + vv) * D_ + k0 + p * 8]) = val;
  }
}

// ---------------------------------------------------------------------------
// joiner_gemm: 128x128 tile, BK=64, 4 waves (2x2 of 64x64), 16x16x32 bf16 MFMA.
// Double-buffered LDS, software-pipelined: issue next K-step's A global loads
// + W global_load_lds BEFORE current K-step's MFMA block; convert+ds_write A
// after; ONE barrier per K-step. A[r][k] = relu(src[b][t0+r/64][k]+tgt[b][r&63][k]).
// ---------------------------------------------------------------------------
__global__ __launch_bounds__(256, 2) void joiner_gemm(
    const float* __restrict__ src, const float* __restrict__ tgt,
    const unsigned short* __restrict__ Wt, const float* __restrict__ bias,
    float* __restrict__ out)
{
  __shared__ __align__(16) short As[2][128 * 64];  // swizzled: row*64 + (chunk^(row&7))*8
  __shared__ __align__(16) short Ws[2][128 * 64];  // linear copy of pre-swizzled Wt rows

  const int tid  = threadIdx.x;
  const int lane = tid & 63;
  const int wid  = tid >> 6;
  const int wm   = wid & 1;          // wave row (2)
  const int wn   = wid >> 1;         // wave col (2)
  const int l15  = lane & 15;
  const int l4   = lane >> 4;

  const int bid    = blockIdx.x;
  const int nt     = bid & 7;        // 8 n-tiles -> one per XCD by default dispatch
  const int mt     = bid >> 3;       // 512 m-tiles
  const int m_base = mt << 7;
  const int bb     = m_base >> 13;            // / (T*U)
  const int t0     = (m_base & 8191) >> 6;    // / U
  const int v0     = nt << 7;

  // A staging assignment: thread -> (row, k-half of 32)
  const int arow  = tid >> 1;                 // 0..127
  const int akh   = (tid & 1) << 5;           // 0 or 32
  const float* srow = src + (size_t)(bb * T_ + t0 + (arow >> 6)) * D_ + akh;
  const float* trow = tgt + (size_t)(bb * U_ + (arow & 63)) * D_ + akh;
  const int aswz  = arow & 7;
  const int apos0 = akh >> 3;                 // 0 or 4

  const int wchunk = (wid << 8) + lane;       // W staging: chunk = wchunk + c*64

  float4 as_[8], ag_[8];                      // prefetch registers (32+32 fp32)
  floatx4 acc[4][4] = {};

#define ALOAD(ks) do {                                                         \
    const float* sp = srow + ((ks) << 6);                                      \
    const float* tp = trow + ((ks) << 6);                                      \
    _Pragma("unroll") for (int c = 0; c < 8; ++c) {                            \
      as_[c] = *reinterpret_cast<const float4*>(sp + c * 4);                   \
      ag_[c] = *reinterpret_cast<const float4*>(tp + c * 4); }                 \
  } while (0)

#define WSTAGE(ks, pbuf) do {                                                  \
    _Pragma("unroll") for (int c = 0; c < 4; ++c) {                            \
      const int chunk = wchunk + (c << 6);                                     \
      const int row   = chunk >> 3;                                            \
      const int pc    = chunk & 7;                                             \
      const unsigned short* g = Wt + (size_t)(v0 + row) * D_ + ((ks) << 6) + pc * 8; \
      __builtin_amdgcn_global_load_lds((const glb_u8_t*)g,                     \
          (lds_u8_t*)&Ws[pbuf][chunk * 8], 16, 0, 0); }                        \
  } while (0)

#define ACVTW(pbuf) do {                                                       \
    _Pragma("unroll") for (int c = 0; c < 4; ++c) {                            \
      const float4 s0 = as_[2 * c], s1 = as_[2 * c + 1];                       \
      const float4 g0 = ag_[2 * c], g1 = ag_[2 * c + 1];                       \
      uint4 v;                                                                 \
      v.x = cvt2(fmaxf(s0.x + g0.x, 0.f), fmaxf(s0.y + g0.y, 0.f));            \
      v.y = cvt2(fmaxf(s0.z + g0.z, 0.f), fmaxf(s0.w + g0.w, 0.f));            \
      v.z = cvt2(fmaxf(s1.x + g1.x, 0.f), fmaxf(s1.y + g1.y, 0.f));            \
      v.w = cvt2(fmaxf(s1.z + g1.z, 0.f), fmaxf(s1.w + g1.w, 0.f));            \
      const int pos = (apos0 + c) ^ aswz;                                      \
      *reinterpret_cast<uint4*>(&As[pbuf][arow * 64 + pos * 8]) = v; }         \
  } while (0)

#define COMPUTE(pbuf) do {                                                     \
    _Pragma("unroll") for (int kk = 0; kk < 2; ++kk) {                         \
      short8v af[4], bfr[4];                                                   \
      _Pragma("unroll") for (int mi = 0; mi < 4; ++mi) {                       \
        const int row = (wm << 6) + (mi << 4) + l15;                           \
        const int pos = ((kk << 2) + l4) ^ (row & 7);                          \
        af[mi] = *reinterpret_cast<const short8v*>(&As[pbuf][row * 64 + pos * 8]); } \
      _Pragma("unroll") for (int ni = 0; ni < 4; ++ni) {                       \
        const int row = (wn << 6) + (ni << 4) + l15;                           \
        const int pos = ((kk << 2) + l4) ^ (row & 7);                          \
        bfr[ni] = *reinterpret_cast<const short8v*>(&Ws[pbuf][row * 64 + pos * 8]); } \
      _Pragma("unroll") for (int mi = 0; mi < 4; ++mi)                         \
        _Pragma("unroll") for (int ni = 0; ni < 4; ++ni)                       \
          acc[mi][ni] = __builtin_amdgcn_mfma_f32_16x16x32_bf16(af[mi], bfr[ni], acc[mi][ni], 0, 0, 0); } \
  } while (0)

  // ---- prologue: fill buffer 0
  ALOAD(0);
  WSTAGE(0, 0);
  ACVTW(0);
  __syncthreads();          // compiler drains vmcnt (gload_lds) + lgkmcnt here

  // ---- main loop: 15 pipelined K-steps + 1 drain
  int buf = 0;
  for (int ks = 0; ks < 15; ++ks) {
    ALOAD(ks + 1);          // issue next A loads (regs)           [vmem]
    WSTAGE(ks + 1, buf ^ 1);// issue next W gload_lds -> buf^1     [vmem]
    COMPUTE(buf);           // ds_read + 32 MFMA (covers latency)
    ACVTW(buf ^ 1);         // waits own A loads, writes buf^1
    __syncthreads();        // single barrier per K-step
    buf ^= 1;
  }
  COMPUTE(buf);

  // ---- epilogue: D row = (lane>>4)*4 + reg, col = lane&15
  const int gcbase = v0 + (wn << 6);
#pragma unroll
  for (int ni = 0; ni < 4; ++ni) {
    const int gc = gcbase + (ni << 4) + l15;
    const float bv = bias[gc];
#pragma unroll
    for (int mi = 0; mi < 4; ++mi) {
      const int gr = m_base + (wm << 6) + (mi << 4) + (l4 << 2);
      float* o = out + (size_t)gr * V_ + gc;
#pragma unroll
      for (int r = 0; r < 4; ++r)
        o[(size_t)r * V_] = acc[mi][ni][r] + bv;
    }
  }
}

extern "C" void kernel_launch(void* const* d_in, const int* in_sizes, int n_in,
                              void* d_out, int out_size, void* d_ws, size_t ws_size,
                              hipStream_t stream) {
  const float* src  = (const float*)d_in[0];   // (B,T,D)
  const float* tgt  = (const float*)d_in[1];   // (B,U,D)
  const float* W    = (const float*)d_in[2];   // (D,V)
  const float* bias = (const float*)d_in[3];   // (V,)
  float* out = (float*)d_out;                  // (B,T,U,V) fp32
  unsigned short* Wt = (unsigned short*)d_ws;  // 2 MB bf16 scratch

  // 1) convert + transpose + pre-swizzle W
  prep_w<<<dim3(D_ / 64, V_ / 64), 256, 0, stream>>>(W, Wt);

  // 2) fused joiner GEMM: grid = (M/128) * (V/128)
  const int grid = (65536 / 128) * (V_ / 128);
  joiner_gemm<<<grid, 256, 0, stream>>>(src, tgt, Wt, bias, out);
}

// Round 4
// 487.196 us; speedup vs baseline: 1.3989x; 1.3989x over previous
//
#include <hip/hip_runtime.h>
#include <hip/hip_bf16.h>
#include <stdint.h>

// Problem constants (fixed by the reference)
#define B_ 8
#define T_ 128
#define U_ 64
#define D_ 1024
#define V_ 1024
// M_total = B*T*U = 65536

typedef __attribute__((ext_vector_type(8))) short short8v;   // 8 bf16 (4 VGPRs)
typedef __attribute__((ext_vector_type(4))) float floatx4;   // MFMA accumulator

typedef __attribute__((address_space(3))) uint8_t lds_u8_t;
typedef __attribute__((address_space(1))) uint8_t glb_u8_t;

// ws layout: [0, 2MB) = Wt bf16 (V x D, pre-swizzled); [2MB, 2MB+128MB) = At bf16 (M x D, pre-swizzled)
#define WT_BYTES   2097152ULL
#define AT_BYTES   134217728ULL
#define WS_NEEDED  (WT_BYTES + AT_BYTES)

// fp32 -> bf16, round-to-nearest-even (scalar)
__device__ __forceinline__ unsigned short f2bf(float f) {
  union { float f; uint32_t u; } c; c.f = f;
  const uint32_t u = c.u;
  return (unsigned short)((u + 0x7fffu + ((u >> 16) & 1u)) >> 16);
}

// packed pair conversion: two fp32 -> one dword of 2 bf16 (RNE)
__device__ __forceinline__ unsigned cvt2(float a, float b) {
  float2 t; t.x = a; t.y = b;
  __hip_bfloat162 h = __float22bfloat162_rn(t);
  union { __hip_bfloat162 h; unsigned u; } c; c.h = h;
  return c.u;
}

// ---------------------------------------------------------------------------
// prep_w: W[k][v] fp32 -> Wt[v][k] bf16, pre-swizzled within each 64-k group
// (position p holds logical chunk p^(v&7)). Grid (D/64, V/64) x 256.
// ---------------------------------------------------------------------------
__global__ void prep_w(const float* __restrict__ W, unsigned short* __restrict__ Wt) {
  __shared__ float tile[64][65];
  const int k0 = blockIdx.x * 64;
  const int v0 = blockIdx.y * 64;
  const int tid = threadIdx.x;
#pragma unroll
  for (int c = 0; c < 4; ++c) {
    const int lin = tid + c * 256;
    const int kk = lin >> 4;
    const int vv = (lin & 15) << 2;
    const float4 f = *reinterpret_cast<const float4*>(&W[(size_t)(k0 + kk) * V_ + v0 + vv]);
    tile[kk][vv + 0] = f.x; tile[kk][vv + 1] = f.y;
    tile[kk][vv + 2] = f.z; tile[kk][vv + 3] = f.w;
  }
  __syncthreads();
#pragma unroll
  for (int c = 0; c < 2; ++c) {
    const int w = tid + c * 256;
    const int vv = w >> 3;
    const int p  = w & 7;
    const int lc = p ^ (vv & 7);
    short8v val;
#pragma unroll
    for (int j = 0; j < 8; ++j) val[j] = (short)f2bf(tile[lc * 8 + j][vv]);
    *reinterpret_cast<short8v*>(&Wt[(size_t)(v0 + vv) * D_ + k0 + p * 8]) = val;
  }
}

// ---------------------------------------------------------------------------
// prep_a: At[m][k] bf16 = relu(src[b][t][k] + tgt[b][u][k]), m=(b*T+t)*U+u,
// rows pre-swizzled: logical k-chunk c stored at position c^(m&7) within each
// 64-k group. Grid: B*T=1024 blocks x 256 threads. Memory-bound (134MB write).
// ---------------------------------------------------------------------------
__global__ __launch_bounds__(256) void prep_a(const float* __restrict__ src,
                                              const float* __restrict__ tgt,
                                              unsigned short* __restrict__ At) {
  const int blk = blockIdx.x;          // = b*T + t
  const int b   = blk >> 7;
  const int tid = threadIdx.x;
  const int rh  = tid >> 7;            // 0/1: odd/even u
  const int k   = (tid & 127) << 3;    // 8-elem k slice, fixed per thread
  const float* sp = src + ((size_t)blk << 10) + k;
  float s0x, s0y, s0z, s0w, s1x, s1y, s1z, s1w;
  { float4 a = *reinterpret_cast<const float4*>(sp);
    float4 c = *reinterpret_cast<const float4*>(sp + 4);
    s0x=a.x; s0y=a.y; s0z=a.z; s0w=a.w; s1x=c.x; s1y=c.y; s1z=c.z; s1w=c.w; }
  const int grp = k >> 6;
  const int ch  = (k >> 3) & 7;
#pragma unroll 4
  for (int u2 = 0; u2 < 32; ++u2) {
    const int u = (u2 << 1) + rh;
    const float* tp = tgt + (((size_t)(b << 6) + u) << 10) + k;
    const float4 t0 = *reinterpret_cast<const float4*>(tp);
    const float4 t1 = *reinterpret_cast<const float4*>(tp + 4);
    uint4 v;
    v.x = cvt2(fmaxf(s0x + t0.x, 0.f), fmaxf(s0y + t0.y, 0.f));
    v.y = cvt2(fmaxf(s0z + t0.z, 0.f), fmaxf(s0w + t0.w, 0.f));
    v.z = cvt2(fmaxf(s1x + t1.x, 0.f), fmaxf(s1y + t1.y, 0.f));
    v.w = cvt2(fmaxf(s1z + t1.z, 0.f), fmaxf(s1w + t1.w, 0.f));
    const size_t row = ((size_t)blk << 6) + u;   // m index
    unsigned short* dst = At + (row << 10) + (grp << 6) + ((ch ^ (int)(row & 7)) << 3);
    *reinterpret_cast<uint4*>(dst) = v;
  }
}

// ---------------------------------------------------------------------------
// joiner_gemm_mat: faithful m97 structure. 128x128 tile, BK=64, 4 waves (2x2),
// both operands staged by global_load_lds (16B) from pre-swizzled At/Wt,
// single-buffered LDS (32KB), 2 barriers per K-step, 32 MFMA/wave/K-step.
// ---------------------------------------------------------------------------
__global__ __launch_bounds__(256) void joiner_gemm_mat(
    const unsigned short* __restrict__ At, const unsigned short* __restrict__ Wt,
    const float* __restrict__ bias, float* __restrict__ out)
{
  __shared__ __align__(16) short As[128 * 64];
  __shared__ __align__(16) short Ws[128 * 64];

  const int tid  = threadIdx.x;
  const int lane = tid & 63;
  const int wid  = tid >> 6;
  const int wm   = wid & 1;
  const int wn   = wid >> 1;
  const int l15  = lane & 15;
  const int l4   = lane >> 4;

  const int bid    = blockIdx.x;
  const int nt     = bid & 7;                // one nt per XCD (default round-robin)
  const int mt     = bid >> 3;
  const int m_base = mt << 7;
  const int v0     = nt << 7;

  const unsigned short* abase = At + ((size_t)m_base << 10);
  const unsigned short* wbase = Wt + ((size_t)v0 << 10);

  const int srow = tid >> 3;                 // staging: chunk c*256+tid -> row, pc
  const int spc  = tid & 7;

  floatx4 acc[4][4] = {};

  for (int ks = 0; ks < 16; ++ks) {
    const int k0 = ks << 6;
#pragma unroll
    for (int c = 0; c < 4; ++c) {
      const int chunk = tid + (c << 8);
      const int row   = srow + (c << 5);
      __builtin_amdgcn_global_load_lds(
          (const glb_u8_t*)(abase + ((size_t)row << 10) + k0 + spc * 8),
          (lds_u8_t*)&As[chunk * 8], 16, 0, 0);
      __builtin_amdgcn_global_load_lds(
          (const glb_u8_t*)(wbase + ((size_t)row << 10) + k0 + spc * 8),
          (lds_u8_t*)&Ws[chunk * 8], 16, 0, 0);
    }
    __syncthreads();

#pragma unroll
    for (int kk = 0; kk < 2; ++kk) {
      short8v af[4], bfr[4];
#pragma unroll
      for (int mi = 0; mi < 4; ++mi) {
        const int row = (wm << 6) + (mi << 4) + l15;
        const int pos = ((kk << 2) + l4) ^ (row & 7);
        af[mi] = *reinterpret_cast<const short8v*>(&As[row * 64 + pos * 8]);
      }
#pragma unroll
      for (int ni = 0; ni < 4; ++ni) {
        const int row = (wn << 6) + (ni << 4) + l15;
        const int pos = ((kk << 2) + l4) ^ (row & 7);
        bfr[ni] = *reinterpret_cast<const short8v*>(&Ws[row * 64 + pos * 8]);
      }
#pragma unroll
      for (int mi = 0; mi < 4; ++mi)
#pragma unroll
        for (int ni = 0; ni < 4; ++ni)
          acc[mi][ni] = __builtin_amdgcn_mfma_f32_16x16x32_bf16(af[mi], bfr[ni], acc[mi][ni], 0, 0, 0);
    }
    __syncthreads();
  }

  const int gcbase = v0 + (wn << 6);
#pragma unroll
  for (int ni = 0; ni < 4; ++ni) {
    const int gc = gcbase + (ni << 4) + l15;
    const float bv = bias[gc];
#pragma unroll
    for (int mi = 0; mi < 4; ++mi) {
      const int gr = m_base + (wm << 6) + (mi << 4) + (l4 << 2);
      float* o = out + (size_t)gr * V_ + gc;
#pragma unroll
      for (int r = 0; r < 4; ++r)
        o[(size_t)r * V_] = acc[mi][ni][r] + bv;
    }
  }
}

// ---------------------------------------------------------------------------
// Fallback (ws too small): round-2 fused kernel — A built on the fly. 451us.
// ---------------------------------------------------------------------------
__global__ __launch_bounds__(256) void joiner_gemm_fused(
    const float* __restrict__ src, const float* __restrict__ tgt,
    const unsigned short* __restrict__ Wt, const float* __restrict__ bias,
    float* __restrict__ out)
{
  __shared__ __align__(16) short As[128 * 64];
  __shared__ __align__(16) short Ws[128 * 64];

  const int tid  = threadIdx.x;
  const int lane = tid & 63;
  const int wid  = tid >> 6;
  const int wm   = wid & 1;
  const int wn   = wid >> 1;
  const int l15  = lane & 15;
  const int l4   = lane >> 4;

  const int bid    = blockIdx.x;
  const int nt     = bid & 7;
  const int mt     = bid >> 3;
  const int m_base = mt << 7;
  const int bb     = m_base >> 13;
  const int t0     = (m_base & 8191) >> 6;
  const int v0     = nt << 7;

  const int arow = tid >> 1;
  const int akh  = (tid & 1) << 5;
  const float* srow = src + (size_t)(bb * T_ + t0 + (arow >> 6)) * D_;
  const float* trow = tgt + (size_t)(bb * U_ + (arow & 63)) * D_;
  const int aswz = arow & 7;

  floatx4 acc[4][4] = {};

  for (int ks = 0; ks < 16; ++ks) {
    const int k0 = ks << 6;
#pragma unroll
    for (int c = 0; c < 4; ++c) {
      const int koff = akh + c * 8;
      const float4 s0 = *reinterpret_cast<const float4*>(srow + k0 + koff);
      const float4 s1 = *reinterpret_cast<const float4*>(srow + k0 + koff + 4);
      const float4 g0 = *reinterpret_cast<const float4*>(trow + k0 + koff);
      const float4 g1 = *reinterpret_cast<const float4*>(trow + k0 + koff + 4);
      uint4 v;
      v.x = cvt2(fmaxf(s0.x + g0.x, 0.f), fmaxf(s0.y + g0.y, 0.f));
      v.y = cvt2(fmaxf(s0.z + g0.z, 0.f), fmaxf(s0.w + g0.w, 0.f));
      v.z = cvt2(fmaxf(s1.x + g1.x, 0.f), fmaxf(s1.y + g1.y, 0.f));
      v.w = cvt2(fmaxf(s1.z + g1.z, 0.f), fmaxf(s1.w + g1.w, 0.f));
      const int pos = (koff >> 3) ^ aswz;
      *reinterpret_cast<uint4*>(&As[arow * 64 + pos * 8]) = v;
    }
#pragma unroll
    for (int c = 0; c < 4; ++c) {
      const int chunk = (wid << 8) + (c << 6) + lane;
      const int row   = chunk >> 3;
      const int pc    = chunk & 7;
      const unsigned short* g = Wt + (size_t)(v0 + row) * D_ + k0 + pc * 8;
      __builtin_amdgcn_global_load_lds((const glb_u8_t*)g, (lds_u8_t*)&Ws[chunk * 8], 16, 0, 0);
    }
    __syncthreads();
#pragma unroll
    for (int kk = 0; kk < 2; ++kk) {
      short8v af[4], bfr[4];
#pragma unroll
      for (int mi = 0; mi < 4; ++mi) {
        const int row = (wm << 6) + (mi << 4) + l15;
        const int pos = ((kk << 2) + l4) ^ (row & 7);
        af[mi] = *reinterpret_cast<const short8v*>(&As[row * 64 + pos * 8]);
      }
#pragma unroll
      for (int ni = 0; ni < 4; ++ni) {
        const int row = (wn << 6) + (ni << 4) + l15;
        const int pos = ((kk << 2) + l4) ^ (row & 7);
        bfr[ni] = *reinterpret_cast<const short8v*>(&Ws[row * 64 + pos * 8]);
      }
#pragma unroll
      for (int mi = 0; mi < 4; ++mi)
#pragma unroll
        for (int ni = 0; ni < 4; ++ni)
          acc[mi][ni] = __builtin_amdgcn_mfma_f32_16x16x32_bf16(af[mi], bfr[ni], acc[mi][ni], 0, 0, 0);
    }
    __syncthreads();
  }

  const int gcbase = v0 + (wn << 6);
#pragma unroll
  for (int ni = 0; ni < 4; ++ni) {
    const int gc = gcbase + (ni << 4) + l15;
    const float bv = bias[gc];
#pragma unroll
    for (int mi = 0; mi < 4; ++mi) {
      const int gr = m_base + (wm << 6) + (mi << 4) + (l4 << 2);
      float* o = out + (size_t)gr * V_ + gc;
#pragma unroll
      for (int r = 0; r < 4; ++r)
        o[(size_t)r * V_] = acc[mi][ni][r] + bv;
    }
  }
}

extern "C" void kernel_launch(void* const* d_in, const int* in_sizes, int n_in,
                              void* d_out, int out_size, void* d_ws, size_t ws_size,
                              hipStream_t stream) {
  const float* src  = (const float*)d_in[0];   // (B,T,D)
  const float* tgt  = (const float*)d_in[1];   // (B,U,D)
  const float* W    = (const float*)d_in[2];   // (D,V)
  const float* bias = (const float*)d_in[3];   // (V,)
  float* out = (float*)d_out;                  // (B,T,U,V) fp32

  unsigned short* Wt = (unsigned short*)d_ws;
  prep_w<<<dim3(D_ / 64, V_ / 64), 256, 0, stream>>>(W, Wt);

  const int grid = (65536 / 128) * (V_ / 128);
  if (ws_size >= WS_NEEDED) {
    unsigned short* At = (unsigned short*)((char*)d_ws + WT_BYTES);
    prep_a<<<B_ * T_, 256, 0, stream>>>(src, tgt, At);
    joiner_gemm_mat<<<grid, 256, 0, stream>>>(At, Wt, bias, out);
  } else {
    joiner_gemm_fused<<<grid, 256, 0, stream>>>(src, tgt, Wt, bias, out);
  }
}

// Round 5
// 436.576 us; speedup vs baseline: 1.5611x; 1.1159x over previous
//
#include <hip/hip_runtime.h>
#include <hip/hip_bf16.h>
#include <stdint.h>

// Problem constants (fixed by the reference)
#define B_ 8
#define T_ 128
#define U_ 64
#define D_ 1024
#define V_ 1024
// M_total = B*T*U = 65536

typedef __attribute__((ext_vector_type(8))) short short8v;   // 8 bf16 (4 VGPRs)
typedef __attribute__((ext_vector_type(4))) float floatx4;   // MFMA accumulator

typedef __attribute__((address_space(3))) uint8_t lds_u8_t;
typedef __attribute__((address_space(1))) uint8_t glb_u8_t;

// fp32 -> bf16, round-to-nearest-even (scalar, prep_w only)
__device__ __forceinline__ unsigned short f2bf(float f) {
  union { float f; uint32_t u; } c; c.f = f;
  const uint32_t u = c.u;
  return (unsigned short)((u + 0x7fffu + ((u >> 16) & 1u)) >> 16);
}

// packed pair conversion: two fp32 -> one dword of 2 bf16 (RNE)
__device__ __forceinline__ unsigned cvt2(float a, float b) {
  float2 t; t.x = a; t.y = b;
  __hip_bfloat162 h = __float22bfloat162_rn(t);
  union { __hip_bfloat162 h; unsigned u; } c; c.h = h;
  return c.u;
}

// ---------------------------------------------------------------------------
// prep_w: W[k][v] fp32 -> Wt[v][k] bf16, pre-swizzled within each 64-k group
// (position p holds logical chunk p^(v&7)). Grid (D/64, V/64) x 256.
// ---------------------------------------------------------------------------
__global__ void prep_w(const float* __restrict__ W, unsigned short* __restrict__ Wt) {
  __shared__ float tile[64][65];
  const int k0 = blockIdx.x * 64;
  const int v0 = blockIdx.y * 64;
  const int tid = threadIdx.x;
#pragma unroll
  for (int c = 0; c < 4; ++c) {
    const int lin = tid + c * 256;
    const int kk = lin >> 4;
    const int vv = (lin & 15) << 2;
    const float4 f = *reinterpret_cast<const float4*>(&W[(size_t)(k0 + kk) * V_ + v0 + vv]);
    tile[kk][vv + 0] = f.x; tile[kk][vv + 1] = f.y;
    tile[kk][vv + 2] = f.z; tile[kk][vv + 3] = f.w;
  }
  __syncthreads();
#pragma unroll
  for (int c = 0; c < 2; ++c) {
    const int w = tid + c * 256;
    const int vv = w >> 3;
    const int p  = w & 7;
    const int lc = p ^ (vv & 7);
    short8v val;
#pragma unroll
    for (int j = 0; j < 8; ++j) val[j] = (short)f2bf(tile[lc * 8 + j][vv]);
    *reinterpret_cast<short8v*>(&Wt[(size_t)(v0 + vv) * D_ + k0 + p * 8]) = val;
  }
}

// ---------------------------------------------------------------------------
// joiner_fused2: BM=128 x BN=256 tile, BK=64, 512 threads = 8 waves (2M x 4N,
// each wave 64x64 out, acc[4][4]). A-tile built in-loop (only 4x redundant
// across the 4 n-tiles), W staged by global_load_lds from pre-swizzled Wt
// (L2-resident). No At materialization -> no 134MB write / 532MB refetch.
// ---------------------------------------------------------------------------
__global__ __launch_bounds__(512) void joiner_fused2(
    const float* __restrict__ src, const float* __restrict__ tgt,
    const unsigned short* __restrict__ Wt, const float* __restrict__ bias,
    float* __restrict__ out)
{
  __shared__ __align__(16) short As[128 * 64];   // 16 KB, swizzled rows
  __shared__ __align__(16) short Ws[256 * 64];   // 32 KB, linear copy of swizzled Wt

  const int tid  = threadIdx.x;
  const int lane = tid & 63;
  const int wid  = tid >> 6;         // 0..7
  const int wm   = wid & 1;          // wave row (2)
  const int wn   = wid >> 1;         // wave col (4)
  const int l15  = lane & 15;
  const int l4   = lane >> 4;

  // bijective XCD swizzle: nwg=2048, 8 XCDs, 256 blocks per XCD chunk
  const int bid = blockIdx.x;
  const int swz = (bid & 7) * 256 + (bid >> 3);
  const int nt     = swz & 3;                 // 4 n-tiles
  const int mt     = swz >> 2;                // 512 m-tiles
  const int m_base = mt << 7;
  const int v0     = nt << 8;
  const int bb     = m_base >> 13;            // / (T*U)
  const int t0     = (m_base & 8191) >> 6;    // / U  (covers t0, t0+1)

  // A-build assignment: 4 threads per row, 2 k-chunks (of 8) each
  const int arow = tid >> 2;                  // 0..127
  const int c0   = (tid & 3) << 1;            // chunks c0, c0+1
  const float* srow = src + (size_t)(bb * T_ + t0 + (arow >> 6)) * D_ + (c0 << 3);
  const float* trow = tgt + (size_t)(bb * U_ + (arow & 63)) * D_ + (c0 << 3);
  const int aswz = arow & 7;

  floatx4 acc[4][4] = {};

  for (int ks = 0; ks < 16; ++ks) {
    const int k0 = ks << 6;

    // ---- stage W: 4 x global_load_lds (16B), linear dest, async
#pragma unroll
    for (int c = 0; c < 4; ++c) {
      const int chunk = tid + (c << 9);            // 0..2047
      const int row   = chunk >> 3;                // v within 256
      const int pc    = chunk & 7;
      const unsigned short* g = Wt + (size_t)(v0 + row) * D_ + k0 + pc * 8;
      __builtin_amdgcn_global_load_lds((const glb_u8_t*)g, (lds_u8_t*)&Ws[chunk * 8], 16, 0, 0);
    }

    // ---- build A: 2 chunks of 8 elems, swizzled 16B ds_writes
#pragma unroll
    for (int cc = 0; cc < 2; ++cc) {
      const float* sp = srow + k0 + (cc << 3);
      const float* tp = trow + k0 + (cc << 3);
      const float4 s0 = *reinterpret_cast<const float4*>(sp);
      const float4 s1 = *reinterpret_cast<const float4*>(sp + 4);
      const float4 g0 = *reinterpret_cast<const float4*>(tp);
      const float4 g1 = *reinterpret_cast<const float4*>(tp + 4);
      uint4 v;
      v.x = cvt2(fmaxf(s0.x + g0.x, 0.f), fmaxf(s0.y + g0.y, 0.f));
      v.y = cvt2(fmaxf(s0.z + g0.z, 0.f), fmaxf(s0.w + g0.w, 0.f));
      v.z = cvt2(fmaxf(s1.x + g1.x, 0.f), fmaxf(s1.y + g1.y, 0.f));
      v.w = cvt2(fmaxf(s1.z + g1.z, 0.f), fmaxf(s1.w + g1.w, 0.f));
      const int pos = (c0 + cc) ^ aswz;
      *reinterpret_cast<uint4*>(&As[arow * 64 + pos * 8]) = v;
    }

    __syncthreads();   // drains vmcnt (gload_lds) + lgkmcnt (ds_write)

    // ---- compute: 2 k-chunks of 32, 16 MFMAs each
#pragma unroll
    for (int kk = 0; kk < 2; ++kk) {
      short8v af[4], bfr[4];
#pragma unroll
      for (int mi = 0; mi < 4; ++mi) {
        const int row = (wm << 6) + (mi << 4) + l15;
        const int pos = ((kk << 2) + l4) ^ (row & 7);
        af[mi] = *reinterpret_cast<const short8v*>(&As[row * 64 + pos * 8]);
      }
#pragma unroll
      for (int ni = 0; ni < 4; ++ni) {
        const int row = (wn << 6) + (ni << 4) + l15;
        const int pos = ((kk << 2) + l4) ^ (row & 7);
        bfr[ni] = *reinterpret_cast<const short8v*>(&Ws[row * 64 + pos * 8]);
      }
#pragma unroll
      for (int mi = 0; mi < 4; ++mi)
#pragma unroll
        for (int ni = 0; ni < 4; ++ni)
          acc[mi][ni] = __builtin_amdgcn_mfma_f32_16x16x32_bf16(af[mi], bfr[ni], acc[mi][ni], 0, 0, 0);
    }
    __syncthreads();
  }

  // ---- epilogue: D row = (lane>>4)*4 + reg, col = lane&15
  const int gcbase = v0 + (wn << 6);
#pragma unroll
  for (int ni = 0; ni < 4; ++ni) {
    const int gc = gcbase + (ni << 4) + l15;
    const float bv = bias[gc];
#pragma unroll
    for (int mi = 0; mi < 4; ++mi) {
      const int gr = m_base + (wm << 6) + (mi << 4) + (l4 << 2);
      float* o = out + (size_t)gr * V_ + gc;
#pragma unroll
      for (int r = 0; r < 4; ++r)
        o[(size_t)r * V_] = acc[mi][ni][r] + bv;
    }
  }
}

extern "C" void kernel_launch(void* const* d_in, const int* in_sizes, int n_in,
                              void* d_out, int out_size, void* d_ws, size_t ws_size,
                              hipStream_t stream) {
  const float* src  = (const float*)d_in[0];   // (B,T,D)
  const float* tgt  = (const float*)d_in[1];   // (B,U,D)
  const float* W    = (const float*)d_in[2];   // (D,V)
  const float* bias = (const float*)d_in[3];   // (V,)
  float* out = (float*)d_out;                  // (B,T,U,V) fp32
  unsigned short* Wt = (unsigned short*)d_ws;  // 2 MB bf16 scratch

  // 1) convert + transpose + pre-swizzle W
  prep_w<<<dim3(D_ / 64, V_ / 64), 256, 0, stream>>>(W, Wt);

  // 2) fused joiner GEMM: grid = (M/128) * (V/256) = 2048 blocks of 512
  const int grid = (65536 / 128) * (V_ / 256);
  joiner_fused2<<<grid, 512, 0, stream>>>(src, tgt, Wt, bias, out);
}